// Round 1
// baseline (2019.161 us; speedup 1.0000x reference)
//
#include <hip/hip_runtime.h>

#define FD 128  // feature dim (both in and out for the GCN layers)

// ---------------------------------------------------------------------------
// 1) degree accumulation: deg[dst] += ew  (self-loop +1 added in dinv pass)
// ---------------------------------------------------------------------------
__global__ __launch_bounds__(256) void deg_kernel(const int* __restrict__ ei,
                                                  const float* __restrict__ ew,
                                                  float* __restrict__ deg, int E) {
    int e = blockIdx.x * blockDim.x + threadIdx.x;
    if (e < E) unsafeAtomicAdd(&deg[ei[E + e]], ew[e]);
}

// ---------------------------------------------------------------------------
// 2) dinv[i] = rsqrt(deg[i] + 1)   (in place; deg >= 0, +1 from self loop)
// ---------------------------------------------------------------------------
__global__ __launch_bounds__(256) void dinv_kernel(float* __restrict__ deg, int N) {
    int i = blockIdx.x * blockDim.x + threadIdx.x;
    if (i < N) deg[i] = rsqrtf(deg[i] + 1.0f);
}

// ---------------------------------------------------------------------------
// 3) GEMM h = X @ W with fused epilogue:
//      hs[row]  = h[row]  * dinv[row]          (pre-scaled messages)
//      agg[row] = hs[row] * dinv[row]          (self-loop contribution, init)
//    block = 256 threads, computes 32 rows x 128 cols, K tiled by 32.
// ---------------------------------------------------------------------------
__global__ __launch_bounds__(256) void gemm_kernel(const float* __restrict__ X,
                                                   const float* __restrict__ W,
                                                   const float* __restrict__ dinv,
                                                   float* __restrict__ hs,
                                                   float* __restrict__ agg, int N) {
    __shared__ float Wt[32][FD];   // [k][col]
    __shared__ float At[32][36];   // [k][row], padded to 36 (16B-aligned rows, few conflicts)

    const int tid = threadIdx.x;
    const int tx = tid & 31;   // col group: cols 4*tx .. 4*tx+3
    const int ty = tid >> 5;   // row group: rows 4*ty .. 4*ty+3 (0..7)
    const int r0 = blockIdx.x * 32;

    float acc[4][4] = {};

    for (int kt = 0; kt < FD; kt += 32) {
        __syncthreads();
        // stage W tile: 32x128 floats = 1024 float4, 4 per thread, coalesced
        #pragma unroll
        for (int i = 0; i < 4; i++) {
            int idx = tid + i * 256;       // float4 index in tile
            int k   = idx >> 5;            // 32 float4 per row
            int c4  = idx & 31;
            float4 w = *(const float4*)&W[(size_t)(kt + k) * FD + c4 * 4];
            *(float4*)&Wt[k][c4 * 4] = w;
        }
        // stage A tile transposed: rows r0..r0+31, k kt..kt+31
        {
            int row_l = tid >> 3;          // 0..31
            int kq    = tid & 7;           // 0..7
            int row   = r0 + row_l;
            float4 a = make_float4(0.f, 0.f, 0.f, 0.f);
            if (row < N) a = *(const float4*)&X[(size_t)row * FD + kt + kq * 4];
            At[kq * 4 + 0][row_l] = a.x;
            At[kq * 4 + 1][row_l] = a.y;
            At[kq * 4 + 2][row_l] = a.z;
            At[kq * 4 + 3][row_l] = a.w;
        }
        __syncthreads();
        #pragma unroll
        for (int k = 0; k < 32; k++) {
            float4 av4 = *(const float4*)&At[k][ty * 4];
            float4 wv4 = *(const float4*)&Wt[k][tx * 4];
            float av[4] = {av4.x, av4.y, av4.z, av4.w};
            float wv[4] = {wv4.x, wv4.y, wv4.z, wv4.w};
            #pragma unroll
            for (int i = 0; i < 4; i++)
                #pragma unroll
                for (int j = 0; j < 4; j++)
                    acc[i][j] = fmaf(av[i], wv[j], acc[i][j]);
        }
    }

    #pragma unroll
    for (int i = 0; i < 4; i++) {
        int row = r0 + ty * 4 + i;
        if (row < N) {
            float dv = dinv[row];
            float4 hv = make_float4(acc[i][0] * dv, acc[i][1] * dv,
                                    acc[i][2] * dv, acc[i][3] * dv);
            *(float4*)&hs[(size_t)row * FD + tx * 4] = hv;
            float4 gv = make_float4(hv.x * dv, hv.y * dv, hv.z * dv, hv.w * dv);
            *(float4*)&agg[(size_t)row * FD + tx * 4] = gv;
        }
    }
}

// ---------------------------------------------------------------------------
// 4) edge scatter: agg[dst] += hs[src] * (ew * dinv[dst])
//    32 threads per edge, float4 per thread, per-float HW atomics.
// ---------------------------------------------------------------------------
__global__ __launch_bounds__(256) void scatter_kernel(const int* __restrict__ ei,
                                                      const float* __restrict__ ew,
                                                      const float* __restrict__ dinv,
                                                      const float* __restrict__ hs,
                                                      float* __restrict__ agg, int E) {
    long long t = (long long)blockIdx.x * blockDim.x + threadIdx.x;
    int e = (int)(t >> 5);
    int q = (int)(t & 31);
    if (e >= E) return;
    int src = ei[e];
    int dst = ei[E + e];
    float nrm = ew[e] * dinv[dst];
    float4 h4 = *(const float4*)&hs[(size_t)src * FD + q * 4];
    float* p = &agg[(size_t)dst * FD + q * 4];
    unsafeAtomicAdd(p + 0, h4.x * nrm);
    unsafeAtomicAdd(p + 1, h4.y * nrm);
    unsafeAtomicAdd(p + 2, h4.z * nrm);
    unsafeAtomicAdd(p + 3, h4.w * nrm);
}

// ---------------------------------------------------------------------------
// 5) per-row relu(agg + b), l2-normalize, accumulate column sums into vec[128]
//    one wave per row (2 floats/lane), per-wave register accum, one atomic
//    flush of 128 floats per block.
// ---------------------------------------------------------------------------
__global__ __launch_bounds__(256) void reduce_kernel(const float* __restrict__ agg,
                                                     const float* __restrict__ b,
                                                     float* __restrict__ vec, int N) {
    __shared__ float accw[4][FD];
    const int tid  = threadIdx.x;
    const int wave = tid >> 6;
    const int lane = tid & 63;

    float2 bb = *(const float2*)&b[lane * 2];
    float a0 = 0.f, a1 = 0.f;

    const int stride = gridDim.x * 4;  // 4 waves per block
    for (int row = blockIdx.x * 4 + wave; row < N; row += stride) {
        float2 v = *(const float2*)&agg[(size_t)row * FD + lane * 2];
        float x0 = fmaxf(v.x + bb.x, 0.f);
        float x1 = fmaxf(v.y + bb.y, 0.f);
        float s = fmaf(x0, x0, x1 * x1);
        #pragma unroll
        for (int off = 32; off; off >>= 1) s += __shfl_xor(s, off);
        float inv = 1.0f / fmaxf(sqrtf(s), 1e-12f);
        a0 = fmaf(x0, inv, a0);
        a1 = fmaf(x1, inv, a1);
    }
    accw[wave][lane * 2 + 0] = a0;
    accw[wave][lane * 2 + 1] = a1;
    __syncthreads();
    if (tid < FD) {
        float s = accw[0][tid] + accw[1][tid] + accw[2][tid] + accw[3][tid];
        unsafeAtomicAdd(&vec[tid], s);
    }
}

// ---------------------------------------------------------------------------
// 6) final MLP: combined(256) @ W1(256x64) + b1 -> relu -> @ W2(64x1) + b2
// ---------------------------------------------------------------------------
__global__ void final_kernel(const float* __restrict__ vec,
                             const float* __restrict__ W1,
                             const float* __restrict__ b1,
                             const float* __restrict__ W2,
                             const float* __restrict__ b2,
                             float* __restrict__ out,
                             float invNnet, float invNdag) {
    int j = threadIdx.x;  // 64 threads
    float h = b1[j];
    for (int k = 0; k < 128; k++)  h = fmaf(vec[k] * invNnet, W1[k * 64 + j], h);
    for (int k = 128; k < 256; k++) h = fmaf(vec[k] * invNdag, W1[k * 64 + j], h);
    h = fmaxf(h, 0.f);
    float p = h * W2[j];
    #pragma unroll
    for (int off = 32; off; off >>= 1) p += __shfl_xor(p, off);
    if (j == 0) out[0] = p + b2[0];
}

// ---------------------------------------------------------------------------
extern "C" void kernel_launch(void* const* d_in, const int* in_sizes, int n_in,
                              void* d_out, int out_size, void* d_ws, size_t ws_size,
                              hipStream_t stream) {
    const float* net_feat = (const float*)d_in[0];
    const int*   net_ei   = (const int*)d_in[1];
    const float* net_ew   = (const float*)d_in[2];
    const float* dag_feat = (const float*)d_in[3];
    const int*   dag_ei   = (const int*)d_in[4];
    const float* dag_ew   = (const float*)d_in[5];
    const float* W_net    = (const float*)d_in[6];
    const float* b_net    = (const float*)d_in[7];
    const float* W_dag    = (const float*)d_in[8];
    const float* b_dag    = (const float*)d_in[9];
    const float* W1       = (const float*)d_in[10];
    const float* b1       = (const float*)d_in[11];
    const float* W2       = (const float*)d_in[12];
    const float* b2       = (const float*)d_in[13];

    const int N_net = in_sizes[0] / FD;
    const int E_net = in_sizes[2];
    const int N_dag = in_sizes[3] / FD;
    const int E_dag = in_sizes[5];

    float* ws = (float*)d_ws;
    size_t o = 0;
    float* h_net   = ws + o; o += (size_t)N_net * FD;
    float* agg_net = ws + o; o += (size_t)N_net * FD;
    float* h_dag   = ws + o; o += (size_t)N_dag * FD;
    float* agg_dag = ws + o; o += (size_t)N_dag * FD;
    float* deg_net = ws + o; o += (size_t)N_net;
    float* deg_dag = ws + o; o += (size_t)N_dag;
    float* vec     = ws + o; o += 256;

    // zero deg_net | deg_dag | vec (contiguous)
    hipMemsetAsync(deg_net, 0, (size_t)(N_net + N_dag + 256) * sizeof(float), stream);

    deg_kernel<<<(E_net + 255) / 256, 256, 0, stream>>>(net_ei, net_ew, deg_net, E_net);
    deg_kernel<<<(E_dag + 255) / 256, 256, 0, stream>>>(dag_ei, dag_ew, deg_dag, E_dag);

    dinv_kernel<<<(N_net + 255) / 256, 256, 0, stream>>>(deg_net, N_net);
    dinv_kernel<<<(N_dag + 255) / 256, 256, 0, stream>>>(deg_dag, N_dag);

    gemm_kernel<<<(N_net + 31) / 32, 256, 0, stream>>>(net_feat, W_net, deg_net, h_net, agg_net, N_net);
    gemm_kernel<<<(N_dag + 31) / 32, 256, 0, stream>>>(dag_feat, W_dag, deg_dag, h_dag, agg_dag, N_dag);

    {
        long long tn = (long long)E_net * 32;
        scatter_kernel<<<(int)((tn + 255) / 256), 256, 0, stream>>>(net_ei, net_ew, deg_net, h_net, agg_net, E_net);
        long long td = (long long)E_dag * 32;
        scatter_kernel<<<(int)((td + 255) / 256), 256, 0, stream>>>(dag_ei, dag_ew, deg_dag, h_dag, agg_dag, E_dag);
    }

    reduce_kernel<<<512, 256, 0, stream>>>(agg_net, b_net, vec, N_net);
    reduce_kernel<<<512, 256, 0, stream>>>(agg_dag, b_dag, vec + 128, N_dag);

    final_kernel<<<1, 64, 0, stream>>>(vec, W1, b1, W2, b2, (float*)d_out,
                                       1.0f / (float)N_net, 1.0f / (float)N_dag);
}

// Round 2
// 594.417 us; speedup vs baseline: 3.3969x; 3.3969x over previous
//
#include <hip/hip_runtime.h>

#define FD 128  // feature dim (both in and out for the GCN layers)

// ---------------------------------------------------------------------------
// 1) weighted degree + unweighted count histogram (by dst)
// ---------------------------------------------------------------------------
__global__ __launch_bounds__(256) void degcnt_kernel(const int* __restrict__ ei,
                                                     const float* __restrict__ ew,
                                                     float* __restrict__ deg,
                                                     int* __restrict__ cnt, int E) {
    int e = blockIdx.x * 256 + threadIdx.x;
    if (e < E) {
        int d = ei[E + e];
        unsafeAtomicAdd(&deg[d], ew[e]);
        atomicAdd(&cnt[d], 1);
    }
}

// ---------------------------------------------------------------------------
// 2) dinv[i] = rsqrt(deg[i] + 1)   (self-loop weight 1)
// ---------------------------------------------------------------------------
__global__ __launch_bounds__(256) void dinv_kernel(float* __restrict__ deg, int N) {
    int i = blockIdx.x * 256 + threadIdx.x;
    if (i < N) deg[i] = rsqrtf(deg[i] + 1.0f);
}

// ---------------------------------------------------------------------------
// 3) exclusive scan of cnt -> off  (3 passes)
// ---------------------------------------------------------------------------
__global__ __launch_bounds__(256) void scan1_kernel(const int* __restrict__ cnt,
                                                    int* __restrict__ bsum, int N) {
    __shared__ int sh[4];
    int i = blockIdx.x * 256 + threadIdx.x;
    int v = (i < N) ? cnt[i] : 0;
    #pragma unroll
    for (int d = 32; d; d >>= 1) v += __shfl_xor(v, d);
    int wave = threadIdx.x >> 6, lane = threadIdx.x & 63;
    if (lane == 0) sh[wave] = v;
    __syncthreads();
    if (threadIdx.x == 0) bsum[blockIdx.x] = sh[0] + sh[1] + sh[2] + sh[3];
}

// single wave, in-place exclusive scan of bsum[0..B)
__global__ void scan2_kernel(int* __restrict__ bsum, int B) {
    int lane = threadIdx.x;  // 64 threads
    int running = 0;
    for (int base = 0; base < B; base += 64) {
        int i = base + lane;
        int v = (i < B) ? bsum[i] : 0;
        int orig = v;
        #pragma unroll
        for (int d = 1; d < 64; d <<= 1) { int t = __shfl_up(v, d); if (lane >= d) v += t; }
        if (i < B) bsum[i] = v - orig + running;
        running += __shfl(v, 63);
    }
}

__global__ __launch_bounds__(256) void scan3_kernel(const int* __restrict__ cnt,
                                                    const int* __restrict__ bsum,
                                                    int* __restrict__ off, int N) {
    __shared__ int wsum[4];
    int i = blockIdx.x * 256 + threadIdx.x;
    int lane = threadIdx.x & 63, wave = threadIdx.x >> 6;
    int v = (i < N) ? cnt[i] : 0;
    int orig = v;
    #pragma unroll
    for (int d = 1; d < 64; d <<= 1) { int t = __shfl_up(v, d); if (lane >= d) v += t; }
    if (lane == 63) wsum[wave] = v;
    __syncthreads();
    int woff = 0;
    for (int w = 0; w < wave; w++) woff += wsum[w];
    if (i < N) off[i] = v - orig + woff + bsum[blockIdx.x];
}

// ---------------------------------------------------------------------------
// 4) bucket edges by dst: elist[pos] = (src, bits(ew)).
//    off is consumed: afterwards off[i] == row_start[i+1].
// ---------------------------------------------------------------------------
__global__ __launch_bounds__(256) void bucket_kernel(const int* __restrict__ ei,
                                                     const float* __restrict__ ew,
                                                     int* __restrict__ off,
                                                     int2* __restrict__ elist, int E) {
    int e = blockIdx.x * 256 + threadIdx.x;
    if (e < E) {
        int dst = ei[E + e];
        int pos = atomicAdd(&off[dst], 1);
        elist[pos] = make_int2(ei[e], __float_as_int(ew[e]));
    }
}

// ---------------------------------------------------------------------------
// 5) GEMM hs = (X @ W) * dinv[row]   (pre-scaled messages)
// ---------------------------------------------------------------------------
__global__ __launch_bounds__(256) void gemm_kernel(const float* __restrict__ X,
                                                   const float* __restrict__ W,
                                                   const float* __restrict__ dinv,
                                                   float* __restrict__ hs, int N) {
    __shared__ float Wt[32][FD];
    __shared__ float At[32][36];

    const int tid = threadIdx.x;
    const int tx = tid & 31;
    const int ty = tid >> 5;
    const int r0 = blockIdx.x * 32;

    float acc[4][4] = {};

    for (int kt = 0; kt < FD; kt += 32) {
        __syncthreads();
        #pragma unroll
        for (int i = 0; i < 4; i++) {
            int idx = tid + i * 256;
            int k   = idx >> 5;
            int c4  = idx & 31;
            float4 w = *(const float4*)&W[(size_t)(kt + k) * FD + c4 * 4];
            *(float4*)&Wt[k][c4 * 4] = w;
        }
        {
            int row_l = tid >> 3;
            int kq    = tid & 7;
            int row   = r0 + row_l;
            float4 a = make_float4(0.f, 0.f, 0.f, 0.f);
            if (row < N) a = *(const float4*)&X[(size_t)row * FD + kt + kq * 4];
            At[kq * 4 + 0][row_l] = a.x;
            At[kq * 4 + 1][row_l] = a.y;
            At[kq * 4 + 2][row_l] = a.z;
            At[kq * 4 + 3][row_l] = a.w;
        }
        __syncthreads();
        #pragma unroll
        for (int k = 0; k < 32; k++) {
            float4 av4 = *(const float4*)&At[k][ty * 4];
            float4 wv4 = *(const float4*)&Wt[k][tx * 4];
            float av[4] = {av4.x, av4.y, av4.z, av4.w};
            float wv[4] = {wv4.x, wv4.y, wv4.z, wv4.w};
            #pragma unroll
            for (int i = 0; i < 4; i++)
                #pragma unroll
                for (int j = 0; j < 4; j++)
                    acc[i][j] = fmaf(av[i], wv[j], acc[i][j]);
        }
    }

    #pragma unroll
    for (int i = 0; i < 4; i++) {
        int row = r0 + ty * 4 + i;
        if (row < N) {
            float dv = dinv[row];
            float4 hv = make_float4(acc[i][0] * dv, acc[i][1] * dv,
                                    acc[i][2] * dv, acc[i][3] * dv);
            *(float4*)&hs[(size_t)row * FD + tx * 4] = hv;
        }
    }
}

// ---------------------------------------------------------------------------
// 6) gather + relu + l2norm + column-mean accumulate, one wave per dst node.
//    agg row lives entirely in registers (float2 per lane).
//    msg = hs[src] * ew * dinv[dst]; self-loop = hs[i] * dinv[i].
// ---------------------------------------------------------------------------
__global__ __launch_bounds__(256) void gather_reduce_kernel(
        const float* __restrict__ hs, const float* __restrict__ dinv,
        const int* __restrict__ off, const int2* __restrict__ elist,
        const float* __restrict__ b, float* __restrict__ vec, int N) {
    __shared__ float accw[4][FD];
    const int tid = threadIdx.x;
    const int wave = tid >> 6;
    const int lane = tid & 63;

    float2 bb = *(const float2*)&b[lane * 2];
    float a0 = 0.f, a1 = 0.f;

    const int stride = gridDim.x * 4;
    for (int i = blockIdx.x * 4 + wave; i < N; i += stride) {
        float dv = dinv[i];
        float2 h = *(const float2*)&hs[(size_t)i * FD + lane * 2];
        float x0 = h.x * dv, x1 = h.y * dv;          // self-loop term
        int js = (i > 0) ? off[i - 1] : 0;           // off consumed by bucket
        int je = off[i];
        for (int j = js; j < je; j++) {
            int2 p = elist[j];
            float w = __int_as_float(p.y) * dv;
            float2 hh = *(const float2*)&hs[(size_t)p.x * FD + lane * 2];
            x0 = fmaf(hh.x, w, x0);
            x1 = fmaf(hh.y, w, x1);
        }
        x0 = fmaxf(x0 + bb.x, 0.f);
        x1 = fmaxf(x1 + bb.y, 0.f);
        float ss = fmaf(x0, x0, x1 * x1);
        #pragma unroll
        for (int o = 32; o; o >>= 1) ss += __shfl_xor(ss, o);
        float inv = 1.0f / fmaxf(sqrtf(ss), 1e-12f);
        a0 = fmaf(x0, inv, a0);
        a1 = fmaf(x1, inv, a1);
    }
    accw[wave][lane * 2 + 0] = a0;
    accw[wave][lane * 2 + 1] = a1;
    __syncthreads();
    if (tid < FD) {
        float s = accw[0][tid] + accw[1][tid] + accw[2][tid] + accw[3][tid];
        unsafeAtomicAdd(&vec[tid], s);
    }
}

// ---------------------------------------------------------------------------
// 7) final MLP: combined(256) @ W1(256x64) + b1 -> relu -> @ W2(64x1) + b2
// ---------------------------------------------------------------------------
__global__ void final_kernel(const float* __restrict__ vec,
                             const float* __restrict__ W1,
                             const float* __restrict__ b1,
                             const float* __restrict__ W2,
                             const float* __restrict__ b2,
                             float* __restrict__ out,
                             float invNnet, float invNdag) {
    int j = threadIdx.x;  // 64 threads
    float h = b1[j];
    for (int k = 0; k < 128; k++)   h = fmaf(vec[k] * invNnet, W1[k * 64 + j], h);
    for (int k = 128; k < 256; k++) h = fmaf(vec[k] * invNdag, W1[k * 64 + j], h);
    h = fmaxf(h, 0.f);
    float p = h * W2[j];
    #pragma unroll
    for (int off = 32; off; off >>= 1) p += __shfl_xor(p, off);
    if (j == 0) out[0] = p + b2[0];
}

// ---------------------------------------------------------------------------
extern "C" void kernel_launch(void* const* d_in, const int* in_sizes, int n_in,
                              void* d_out, int out_size, void* d_ws, size_t ws_size,
                              hipStream_t stream) {
    const float* net_feat = (const float*)d_in[0];
    const int*   net_ei   = (const int*)d_in[1];
    const float* net_ew   = (const float*)d_in[2];
    const float* dag_feat = (const float*)d_in[3];
    const int*   dag_ei   = (const int*)d_in[4];
    const float* dag_ew   = (const float*)d_in[5];
    const float* b_net    = (const float*)d_in[7];
    const float* W_net    = (const float*)d_in[6];
    const float* W_dag    = (const float*)d_in[8];
    const float* b_dag    = (const float*)d_in[9];
    const float* W1       = (const float*)d_in[10];
    const float* b1       = (const float*)d_in[11];
    const float* W2       = (const float*)d_in[12];
    const float* b2       = (const float*)d_in[13];

    const int N_net = in_sizes[0] / FD;
    const int E_net = in_sizes[2];
    const int N_dag = in_sizes[3] / FD;
    const int E_dag = in_sizes[5];
    const int Bn = (N_net + 255) / 256;
    const int Bd = (N_dag + 255) / 256;

    float* ws = (float*)d_ws;
    size_t o = 0;
    float* hs_net = ws + o; o += (size_t)N_net * FD;
    float* hs_dag = ws + o; o += (size_t)N_dag * FD;
    // zeroed region: deg_net | deg_dag | cnt_net | cnt_dag | vec
    float* deg_net = ws + o; o += N_net;
    float* deg_dag = ws + o; o += N_dag;
    int*   cnt_net = (int*)(ws + o); o += N_net;
    int*   cnt_dag = (int*)(ws + o); o += N_dag;
    float* vec     = ws + o; o += 256;
    size_t zcount = (size_t)2 * (N_net + N_dag) + 256;
    int*   off_net  = (int*)(ws + o); o += N_net;
    int*   off_dag  = (int*)(ws + o); o += N_dag;
    int*   bsum_net = (int*)(ws + o); o += (size_t)(Bn + 1) & ~(size_t)1;
    int*   bsum_dag = (int*)(ws + o); o += (size_t)(Bd + 1) & ~(size_t)1;
    int2*  elist_net = (int2*)(ws + o); o += (size_t)2 * E_net;
    int2*  elist_dag = (int2*)(ws + o); o += (size_t)2 * E_dag;

    hipMemsetAsync(deg_net, 0, zcount * sizeof(float), stream);

    degcnt_kernel<<<(E_net + 255) / 256, 256, 0, stream>>>(net_ei, net_ew, deg_net, cnt_net, E_net);
    degcnt_kernel<<<(E_dag + 255) / 256, 256, 0, stream>>>(dag_ei, dag_ew, deg_dag, cnt_dag, E_dag);

    dinv_kernel<<<(N_net + 255) / 256, 256, 0, stream>>>(deg_net, N_net);
    dinv_kernel<<<(N_dag + 255) / 256, 256, 0, stream>>>(deg_dag, N_dag);

    scan1_kernel<<<Bn, 256, 0, stream>>>(cnt_net, bsum_net, N_net);
    scan1_kernel<<<Bd, 256, 0, stream>>>(cnt_dag, bsum_dag, N_dag);
    scan2_kernel<<<1, 64, 0, stream>>>(bsum_net, Bn);
    scan2_kernel<<<1, 64, 0, stream>>>(bsum_dag, Bd);
    scan3_kernel<<<Bn, 256, 0, stream>>>(cnt_net, bsum_net, off_net, N_net);
    scan3_kernel<<<Bd, 256, 0, stream>>>(cnt_dag, bsum_dag, off_dag, N_dag);

    bucket_kernel<<<(E_net + 255) / 256, 256, 0, stream>>>(net_ei, net_ew, off_net, elist_net, E_net);
    bucket_kernel<<<(E_dag + 255) / 256, 256, 0, stream>>>(dag_ei, dag_ew, off_dag, elist_dag, E_dag);

    gemm_kernel<<<(N_net + 31) / 32, 256, 0, stream>>>(net_feat, W_net, deg_net, hs_net, N_net);
    gemm_kernel<<<(N_dag + 31) / 32, 256, 0, stream>>>(dag_feat, W_dag, deg_dag, hs_dag, N_dag);

    gather_reduce_kernel<<<1024, 256, 0, stream>>>(hs_net, deg_net, off_net, elist_net,
                                                   b_net, vec, N_net);
    gather_reduce_kernel<<<1024, 256, 0, stream>>>(hs_dag, deg_dag, off_dag, elist_dag,
                                                   b_dag, vec + 128, N_dag);

    final_kernel<<<1, 64, 0, stream>>>(vec, W1, b1, W2, b2, (float*)d_out,
                                       1.0f / (float)N_net, 1.0f / (float)N_dag);
}

// Round 3
// 493.255 us; speedup vs baseline: 4.0935x; 1.2051x over previous
//
#include <hip/hip_runtime.h>

#define FD 128  // feature dim (both in and out for the GCN layers)

// ---------------------------------------------------------------------------
// 1) weighted degree + count histogram (by dst), both graphs in one launch
// ---------------------------------------------------------------------------
__global__ __launch_bounds__(256) void degcnt_both(
        const int* __restrict__ ei_n, const float* __restrict__ ew_n,
        float* __restrict__ deg_n, int* __restrict__ cnt_n, int E_n, int GBn,
        const int* __restrict__ ei_d, const float* __restrict__ ew_d,
        float* __restrict__ deg_d, int* __restrict__ cnt_d, int E_d) {
    int b = blockIdx.x;
    const int* ei; const float* ew; float* deg; int* cnt; int E, e;
    if (b < GBn) { ei = ei_n; ew = ew_n; deg = deg_n; cnt = cnt_n; E = E_n;
                   e = b * 256 + threadIdx.x; }
    else         { ei = ei_d; ew = ew_d; deg = deg_d; cnt = cnt_d; E = E_d;
                   e = (b - GBn) * 256 + threadIdx.x; }
    if (e < E) {
        int d = ei[E + e];
        unsafeAtomicAdd(&deg[d], ew[e]);
        atomicAdd(&cnt[d], 1);
    }
}

// ---------------------------------------------------------------------------
// 2) dinv[i] = rsqrt(deg[i] + 1)  — deg_net|deg_dag contiguous, one launch
// ---------------------------------------------------------------------------
__global__ __launch_bounds__(256) void dinv_kernel(float* __restrict__ deg, int N) {
    int i = blockIdx.x * 256 + threadIdx.x;
    if (i < N) deg[i] = rsqrtf(deg[i] + 1.0f);
}

// ---------------------------------------------------------------------------
// 3) exclusive scan of cnt -> off (3 passes), both graphs per launch
// ---------------------------------------------------------------------------
__global__ __launch_bounds__(256) void scan1_both(
        const int* __restrict__ cnt_n, int* __restrict__ bsum_n, int N_n, int Bn,
        const int* __restrict__ cnt_d, int* __restrict__ bsum_d, int N_d) {
    __shared__ int sh[4];
    int b = blockIdx.x;
    const int* cnt; int* bsum; int N, bi;
    if (b < Bn) { cnt = cnt_n; bsum = bsum_n; N = N_n; bi = b; }
    else        { cnt = cnt_d; bsum = bsum_d; N = N_d; bi = b - Bn; }
    int i = bi * 256 + threadIdx.x;
    int v = (i < N) ? cnt[i] : 0;
    #pragma unroll
    for (int d = 32; d; d >>= 1) v += __shfl_xor(v, d);
    int wave = threadIdx.x >> 6, lane = threadIdx.x & 63;
    if (lane == 0) sh[wave] = v;
    __syncthreads();
    if (threadIdx.x == 0) bsum[bi] = sh[0] + sh[1] + sh[2] + sh[3];
}

// 2 blocks x 64 threads: block 0 scans bsum_net, block 1 scans bsum_dag
__global__ void scan2_both(int* __restrict__ bsum_n, int Bn,
                           int* __restrict__ bsum_d, int Bd) {
    int* bsum = blockIdx.x ? bsum_d : bsum_n;
    int B     = blockIdx.x ? Bd : Bn;
    int lane = threadIdx.x;
    int running = 0;
    for (int base = 0; base < B; base += 64) {
        int i = base + lane;
        int v = (i < B) ? bsum[i] : 0;
        int orig = v;
        #pragma unroll
        for (int d = 1; d < 64; d <<= 1) { int t = __shfl_up(v, d); if (lane >= d) v += t; }
        if (i < B) bsum[i] = v - orig + running;
        running += __shfl(v, 63);
    }
}

__global__ __launch_bounds__(256) void scan3_both(
        const int* __restrict__ cnt_n, const int* __restrict__ bsum_n,
        int* __restrict__ off_n, int N_n, int Bn,
        const int* __restrict__ cnt_d, const int* __restrict__ bsum_d,
        int* __restrict__ off_d, int N_d) {
    __shared__ int wsum[4];
    int b = blockIdx.x;
    const int *cnt, *bsum; int *off; int N, bi;
    if (b < Bn) { cnt = cnt_n; bsum = bsum_n; off = off_n; N = N_n; bi = b; }
    else        { cnt = cnt_d; bsum = bsum_d; off = off_d; N = N_d; bi = b - Bn; }
    int i = bi * 256 + threadIdx.x;
    int lane = threadIdx.x & 63, wave = threadIdx.x >> 6;
    int v = (i < N) ? cnt[i] : 0;
    int orig = v;
    #pragma unroll
    for (int d = 1; d < 64; d <<= 1) { int t = __shfl_up(v, d); if (lane >= d) v += t; }
    if (lane == 63) wsum[wave] = v;
    __syncthreads();
    int woff = 0;
    for (int w = 0; w < wave; w++) woff += wsum[w];
    if (i < N) off[i] = v - orig + woff + bsum[bi];
}

// ---------------------------------------------------------------------------
// 4) bucket edges by dst; off consumed: afterwards off[i] == row_end[i]
// ---------------------------------------------------------------------------
__global__ __launch_bounds__(256) void bucket_both(
        const int* __restrict__ ei_n, const float* __restrict__ ew_n,
        int* __restrict__ off_n, int2* __restrict__ el_n, int E_n, int GBn,
        const int* __restrict__ ei_d, const float* __restrict__ ew_d,
        int* __restrict__ off_d, int2* __restrict__ el_d, int E_d) {
    int b = blockIdx.x;
    const int* ei; const float* ew; int* off; int2* el; int E, e;
    if (b < GBn) { ei = ei_n; ew = ew_n; off = off_n; el = el_n; E = E_n;
                   e = b * 256 + threadIdx.x; }
    else         { ei = ei_d; ew = ew_d; off = off_d; el = el_d; E = E_d;
                   e = (b - GBn) * 256 + threadIdx.x; }
    if (e < E) {
        int dst = ei[E + e];
        int pos = atomicAdd(&off[dst], 1);
        el[pos] = make_int2(ei[e], __float_as_int(ew[e]));
    }
}

// ---------------------------------------------------------------------------
// 5) GEMM hs = (X @ W) * dinv[row], both graphs in one launch
// ---------------------------------------------------------------------------
__global__ __launch_bounds__(256) void gemm_both(
        const float* __restrict__ X_n, const float* __restrict__ W_n,
        const float* __restrict__ dinv_n, float* __restrict__ hs_n, int N_n, int Gn,
        const float* __restrict__ X_d, const float* __restrict__ W_d,
        const float* __restrict__ dinv_d, float* __restrict__ hs_d, int N_d) {
    __shared__ float Wt[32][FD];
    __shared__ float At[32][36];

    const float *X, *W, *dinv; float* hs; int N, r0;
    if (blockIdx.x < Gn) { X = X_n; W = W_n; dinv = dinv_n; hs = hs_n; N = N_n;
                           r0 = blockIdx.x * 32; }
    else                 { X = X_d; W = W_d; dinv = dinv_d; hs = hs_d; N = N_d;
                           r0 = (blockIdx.x - Gn) * 32; }

    const int tid = threadIdx.x;
    const int tx = tid & 31;
    const int ty = tid >> 5;

    float acc[4][4] = {};

    for (int kt = 0; kt < FD; kt += 32) {
        __syncthreads();
        #pragma unroll
        for (int i = 0; i < 4; i++) {
            int idx = tid + i * 256;
            int k   = idx >> 5;
            int c4  = idx & 31;
            float4 w = *(const float4*)&W[(size_t)(kt + k) * FD + c4 * 4];
            *(float4*)&Wt[k][c4 * 4] = w;
        }
        {
            int row_l = tid >> 3;
            int kq    = tid & 7;
            int row   = r0 + row_l;
            float4 a = make_float4(0.f, 0.f, 0.f, 0.f);
            if (row < N) a = *(const float4*)&X[(size_t)row * FD + kt + kq * 4];
            At[kq * 4 + 0][row_l] = a.x;
            At[kq * 4 + 1][row_l] = a.y;
            At[kq * 4 + 2][row_l] = a.z;
            At[kq * 4 + 3][row_l] = a.w;
        }
        __syncthreads();
        #pragma unroll
        for (int k = 0; k < 32; k++) {
            float4 av4 = *(const float4*)&At[k][ty * 4];
            float4 wv4 = *(const float4*)&Wt[k][tx * 4];
            float av[4] = {av4.x, av4.y, av4.z, av4.w};
            float wv[4] = {wv4.x, wv4.y, wv4.z, wv4.w};
            #pragma unroll
            for (int i = 0; i < 4; i++)
                #pragma unroll
                for (int j = 0; j < 4; j++)
                    acc[i][j] = fmaf(av[i], wv[j], acc[i][j]);
        }
    }

    #pragma unroll
    for (int i = 0; i < 4; i++) {
        int row = r0 + ty * 4 + i;
        if (row < N) {
            float dv = dinv[row];
            float4 hv = make_float4(acc[i][0] * dv, acc[i][1] * dv,
                                    acc[i][2] * dv, acc[i][3] * dv);
            *(float4*)&hs[(size_t)row * FD + tx * 4] = hv;
        }
    }
}

// ---------------------------------------------------------------------------
// 6) gather + relu + l2norm + column-mean accumulate; one wave per node;
//    both graphs in one grid-stride loop; 4-deep pipelined edge loop.
// ---------------------------------------------------------------------------
__global__ __launch_bounds__(256) void gather_reduce_both(
        const float* __restrict__ hs_n, const float* __restrict__ dinv_n,
        const int* __restrict__ off_n, const int2* __restrict__ el_n,
        const float* __restrict__ b_n, int N_n,
        const float* __restrict__ hs_d, const float* __restrict__ dinv_d,
        const int* __restrict__ off_d, const int2* __restrict__ el_d,
        const float* __restrict__ b_d, int N_d,
        float* __restrict__ vec) {
    __shared__ float accw[4][2 * FD];
    const int tid = threadIdx.x;
    const int wave = tid >> 6;
    const int lane = tid & 63;

    float2 bbn = *(const float2*)&b_n[lane * 2];
    float2 bbd = *(const float2*)&b_d[lane * 2];
    float an0 = 0.f, an1 = 0.f, ad0 = 0.f, ad1 = 0.f;

    const int total = N_n + N_d;
    const int stride = gridDim.x * 4;
    for (int t = blockIdx.x * 4 + wave; t < total; t += stride) {
        const bool isn = t < N_n;
        const int i = isn ? t : t - N_n;
        const float* hs   = isn ? hs_n : hs_d;
        const float* dinv = isn ? dinv_n : dinv_d;
        const int*   off  = isn ? off_n : off_d;
        const int2*  el   = isn ? el_n : el_d;

        float dv = dinv[i];
        float2 h = *(const float2*)&hs[(size_t)i * FD + lane * 2];
        float x0 = h.x * dv, x1 = h.y * dv;          // self-loop term
        int js = i ? off[i - 1] : 0;
        int je = off[i];
        int j = js;
        for (; j + 4 <= je; j += 4) {
            int2 p0 = el[j], p1 = el[j + 1], p2 = el[j + 2], p3 = el[j + 3];
            float2 h0 = *(const float2*)&hs[(size_t)p0.x * FD + lane * 2];
            float2 h1 = *(const float2*)&hs[(size_t)p1.x * FD + lane * 2];
            float2 h2 = *(const float2*)&hs[(size_t)p2.x * FD + lane * 2];
            float2 h3 = *(const float2*)&hs[(size_t)p3.x * FD + lane * 2];
            float w0 = __int_as_float(p0.y) * dv;
            float w1 = __int_as_float(p1.y) * dv;
            float w2 = __int_as_float(p2.y) * dv;
            float w3 = __int_as_float(p3.y) * dv;
            x0 = fmaf(h0.x, w0, x0); x1 = fmaf(h0.y, w0, x1);
            x0 = fmaf(h1.x, w1, x0); x1 = fmaf(h1.y, w1, x1);
            x0 = fmaf(h2.x, w2, x0); x1 = fmaf(h2.y, w2, x1);
            x0 = fmaf(h3.x, w3, x0); x1 = fmaf(h3.y, w3, x1);
        }
        if (j + 2 <= je) {
            int2 p0 = el[j], p1 = el[j + 1];
            float2 h0 = *(const float2*)&hs[(size_t)p0.x * FD + lane * 2];
            float2 h1 = *(const float2*)&hs[(size_t)p1.x * FD + lane * 2];
            float w0 = __int_as_float(p0.y) * dv;
            float w1 = __int_as_float(p1.y) * dv;
            x0 = fmaf(h0.x, w0, x0); x1 = fmaf(h0.y, w0, x1);
            x0 = fmaf(h1.x, w1, x0); x1 = fmaf(h1.y, w1, x1);
            j += 2;
        }
        if (j < je) {
            int2 p0 = el[j];
            float2 h0 = *(const float2*)&hs[(size_t)p0.x * FD + lane * 2];
            float w0 = __int_as_float(p0.y) * dv;
            x0 = fmaf(h0.x, w0, x0); x1 = fmaf(h0.y, w0, x1);
        }
        float2 bb = isn ? bbn : bbd;
        x0 = fmaxf(x0 + bb.x, 0.f);
        x1 = fmaxf(x1 + bb.y, 0.f);
        float ss = fmaf(x0, x0, x1 * x1);
        #pragma unroll
        for (int o = 32; o; o >>= 1) ss += __shfl_xor(ss, o);
        float inv = 1.0f / fmaxf(sqrtf(ss), 1e-12f);
        if (isn) { an0 = fmaf(x0, inv, an0); an1 = fmaf(x1, inv, an1); }
        else     { ad0 = fmaf(x0, inv, ad0); ad1 = fmaf(x1, inv, ad1); }
    }
    accw[wave][lane * 2 + 0] = an0;
    accw[wave][lane * 2 + 1] = an1;
    accw[wave][FD + lane * 2 + 0] = ad0;
    accw[wave][FD + lane * 2 + 1] = ad1;
    __syncthreads();
    if (tid < 2 * FD) {
        float s = accw[0][tid] + accw[1][tid] + accw[2][tid] + accw[3][tid];
        unsafeAtomicAdd(&vec[tid], s);
    }
}

// ---------------------------------------------------------------------------
// 7) final MLP: combined(256) @ W1(256x64) + b1 -> relu -> @ W2(64x1) + b2
// ---------------------------------------------------------------------------
__global__ void final_kernel(const float* __restrict__ vec,
                             const float* __restrict__ W1,
                             const float* __restrict__ b1,
                             const float* __restrict__ W2,
                             const float* __restrict__ b2,
                             float* __restrict__ out,
                             float invNnet, float invNdag) {
    int j = threadIdx.x;  // 64 threads
    float h = b1[j];
    for (int k = 0; k < 128; k++)   h = fmaf(vec[k] * invNnet, W1[k * 64 + j], h);
    for (int k = 128; k < 256; k++) h = fmaf(vec[k] * invNdag, W1[k * 64 + j], h);
    h = fmaxf(h, 0.f);
    float p = h * W2[j];
    #pragma unroll
    for (int off = 32; off; off >>= 1) p += __shfl_xor(p, off);
    if (j == 0) out[0] = p + b2[0];
}

// ---------------------------------------------------------------------------
extern "C" void kernel_launch(void* const* d_in, const int* in_sizes, int n_in,
                              void* d_out, int out_size, void* d_ws, size_t ws_size,
                              hipStream_t stream) {
    const float* net_feat = (const float*)d_in[0];
    const int*   net_ei   = (const int*)d_in[1];
    const float* net_ew   = (const float*)d_in[2];
    const float* dag_feat = (const float*)d_in[3];
    const int*   dag_ei   = (const int*)d_in[4];
    const float* dag_ew   = (const float*)d_in[5];
    const float* W_net    = (const float*)d_in[6];
    const float* b_net    = (const float*)d_in[7];
    const float* W_dag    = (const float*)d_in[8];
    const float* b_dag    = (const float*)d_in[9];
    const float* W1       = (const float*)d_in[10];
    const float* b1       = (const float*)d_in[11];
    const float* W2       = (const float*)d_in[12];
    const float* b2       = (const float*)d_in[13];

    const int N_net = in_sizes[0] / FD;
    const int E_net = in_sizes[2];
    const int N_dag = in_sizes[3] / FD;
    const int E_dag = in_sizes[5];
    const int Bn  = (N_net + 255) / 256, Bd  = (N_dag + 255) / 256;
    const int GBn = (E_net + 255) / 256, GBd = (E_dag + 255) / 256;
    const int Gn  = (N_net + 31) / 32,  Gd  = (N_dag + 31) / 32;

    float* ws = (float*)d_ws;
    size_t o = 0;
    float* hs_net = ws + o; o += (size_t)N_net * FD;
    float* hs_dag = ws + o; o += (size_t)N_dag * FD;
    // zeroed region: deg_net | deg_dag | cnt_net | cnt_dag | vec
    float* deg_net = ws + o; o += N_net;
    float* deg_dag = ws + o; o += N_dag;
    int*   cnt_net = (int*)(ws + o); o += N_net;
    int*   cnt_dag = (int*)(ws + o); o += N_dag;
    float* vec     = ws + o; o += 256;
    size_t zcount = (size_t)2 * (N_net + N_dag) + 256;
    int*   off_net  = (int*)(ws + o); o += N_net;
    int*   off_dag  = (int*)(ws + o); o += N_dag;
    int*   bsum_net = (int*)(ws + o); o += (size_t)(Bn + 1) & ~(size_t)1;
    int*   bsum_dag = (int*)(ws + o); o += (size_t)(Bd + 1) & ~(size_t)1;
    int2*  elist_net = (int2*)(ws + o); o += (size_t)2 * E_net;
    int2*  elist_dag = (int2*)(ws + o); o += (size_t)2 * E_dag;

    hipMemsetAsync(deg_net, 0, zcount * sizeof(float), stream);

    degcnt_both<<<GBn + GBd, 256, 0, stream>>>(net_ei, net_ew, deg_net, cnt_net, E_net, GBn,
                                               dag_ei, dag_ew, deg_dag, cnt_dag, E_dag);

    dinv_kernel<<<(N_net + N_dag + 255) / 256, 256, 0, stream>>>(deg_net, N_net + N_dag);

    scan1_both<<<Bn + Bd, 256, 0, stream>>>(cnt_net, bsum_net, N_net, Bn,
                                            cnt_dag, bsum_dag, N_dag);
    scan2_both<<<2, 64, 0, stream>>>(bsum_net, Bn, bsum_dag, Bd);
    scan3_both<<<Bn + Bd, 256, 0, stream>>>(cnt_net, bsum_net, off_net, N_net, Bn,
                                            cnt_dag, bsum_dag, off_dag, N_dag);

    bucket_both<<<GBn + GBd, 256, 0, stream>>>(net_ei, net_ew, off_net, elist_net, E_net, GBn,
                                               dag_ei, dag_ew, off_dag, elist_dag, E_dag);

    gemm_both<<<Gn + Gd, 256, 0, stream>>>(net_feat, W_net, deg_net, hs_net, N_net, Gn,
                                           dag_feat, W_dag, deg_dag, hs_dag, N_dag);

    gather_reduce_both<<<2048, 256, 0, stream>>>(
        hs_net, deg_net, off_net, elist_net, b_net, N_net,
        hs_dag, deg_dag, off_dag, elist_dag, b_dag, N_dag, vec);

    final_kernel<<<1, 64, 0, stream>>>(vec, W1, b1, W2, b2, (float*)d_out,
                                       1.0f / (float)N_net, 1.0f / (float)N_dag);
}

// Round 4
// 480.610 us; speedup vs baseline: 4.2012x; 1.0263x over previous
//
#include <hip/hip_runtime.h>

#define FD 128  // feature dim (both in and out for the GCN layers)

// ---------------------------------------------------------------------------
// 1) weighted degree + count histogram (by dst), both graphs in one launch
// ---------------------------------------------------------------------------
__global__ __launch_bounds__(256) void degcnt_both(
        const int* __restrict__ ei_n, const float* __restrict__ ew_n,
        float* __restrict__ deg_n, int* __restrict__ cnt_n, int E_n, int GBn,
        const int* __restrict__ ei_d, const float* __restrict__ ew_d,
        float* __restrict__ deg_d, int* __restrict__ cnt_d, int E_d) {
    int b = blockIdx.x;
    const int* ei; const float* ew; float* deg; int* cnt; int E, e;
    if (b < GBn) { ei = ei_n; ew = ew_n; deg = deg_n; cnt = cnt_n; E = E_n;
                   e = b * 256 + threadIdx.x; }
    else         { ei = ei_d; ew = ew_d; deg = deg_d; cnt = cnt_d; E = E_d;
                   e = (b - GBn) * 256 + threadIdx.x; }
    if (e < E) {
        int d = ei[E + e];
        unsafeAtomicAdd(&deg[d], ew[e]);
        atomicAdd(&cnt[d], 1);
    }
}

// ---------------------------------------------------------------------------
// 2) block sums of cnt + fused dinv = rsqrt(deg+1)  (both graphs per launch)
// ---------------------------------------------------------------------------
__global__ __launch_bounds__(256) void scan1_both(
        const int* __restrict__ cnt_n, int* __restrict__ bsum_n,
        float* __restrict__ deg_n, int N_n, int Bn,
        const int* __restrict__ cnt_d, int* __restrict__ bsum_d,
        float* __restrict__ deg_d, int N_d) {
    __shared__ int sh[4];
    int b = blockIdx.x;
    const int* cnt; int* bsum; float* deg; int N, bi;
    if (b < Bn) { cnt = cnt_n; bsum = bsum_n; deg = deg_n; N = N_n; bi = b; }
    else        { cnt = cnt_d; bsum = bsum_d; deg = deg_d; N = N_d; bi = b - Bn; }
    int i = bi * 256 + threadIdx.x;
    int v = 0;
    if (i < N) {
        v = cnt[i];
        deg[i] = rsqrtf(deg[i] + 1.0f);   // fused dinv
    }
    int vv = v;
    #pragma unroll
    for (int d = 32; d; d >>= 1) vv += __shfl_xor(vv, d);
    int wave = threadIdx.x >> 6, lane = threadIdx.x & 63;
    if (lane == 0) sh[wave] = vv;
    __syncthreads();
    if (threadIdx.x == 0) bsum[bi] = sh[0] + sh[1] + sh[2] + sh[3];
}

// 2 blocks x 64 threads: block 0 scans bsum_net, block 1 scans bsum_dag
__global__ void scan2_both(int* __restrict__ bsum_n, int Bn,
                           int* __restrict__ bsum_d, int Bd) {
    int* bsum = blockIdx.x ? bsum_d : bsum_n;
    int B     = blockIdx.x ? Bd : Bn;
    int lane = threadIdx.x;
    int running = 0;
    for (int base = 0; base < B; base += 64) {
        int i = base + lane;
        int v = (i < B) ? bsum[i] : 0;
        int orig = v;
        #pragma unroll
        for (int d = 1; d < 64; d <<= 1) { int t = __shfl_up(v, d); if (lane >= d) v += t; }
        if (i < B) bsum[i] = v - orig + running;
        running += __shfl(v, 63);
    }
}

__global__ __launch_bounds__(256) void scan3_both(
        const int* __restrict__ cnt_n, const int* __restrict__ bsum_n,
        int* __restrict__ off_n, int N_n, int Bn,
        const int* __restrict__ cnt_d, const int* __restrict__ bsum_d,
        int* __restrict__ off_d, int N_d) {
    __shared__ int wsum[4];
    int b = blockIdx.x;
    const int *cnt, *bsum; int *off; int N, bi;
    if (b < Bn) { cnt = cnt_n; bsum = bsum_n; off = off_n; N = N_n; bi = b; }
    else        { cnt = cnt_d; bsum = bsum_d; off = off_d; N = N_d; bi = b - Bn; }
    int i = bi * 256 + threadIdx.x;
    int lane = threadIdx.x & 63, wave = threadIdx.x >> 6;
    int v = (i < N) ? cnt[i] : 0;
    int orig = v;
    #pragma unroll
    for (int d = 1; d < 64; d <<= 1) { int t = __shfl_up(v, d); if (lane >= d) v += t; }
    if (lane == 63) wsum[wave] = v;
    __syncthreads();
    int woff = 0;
    for (int w = 0; w < wave; w++) woff += wsum[w];
    if (i < N) off[i] = v - orig + woff + bsum[bi];
}

// ---------------------------------------------------------------------------
// 3) bucket edges by dst; off consumed: afterwards off[i] == row_end[i]
// ---------------------------------------------------------------------------
__global__ __launch_bounds__(256) void bucket_both(
        const int* __restrict__ ei_n, const float* __restrict__ ew_n,
        int* __restrict__ off_n, int2* __restrict__ el_n, int E_n, int GBn,
        const int* __restrict__ ei_d, const float* __restrict__ ew_d,
        int* __restrict__ off_d, int2* __restrict__ el_d, int E_d) {
    int b = blockIdx.x;
    const int* ei; const float* ew; int* off; int2* el; int E, e;
    if (b < GBn) { ei = ei_n; ew = ew_n; off = off_n; el = el_n; E = E_n;
                   e = b * 256 + threadIdx.x; }
    else         { ei = ei_d; ew = ew_d; off = off_d; el = el_d; E = E_d;
                   e = (b - GBn) * 256 + threadIdx.x; }
    if (e < E) {
        int dst = ei[E + e];
        int pos = atomicAdd(&off[dst], 1);
        el[pos] = make_int2(ei[e], __float_as_int(ew[e]));
    }
}

// ---------------------------------------------------------------------------
// 4) GEMM hs = (X @ W) * dinv[row], both graphs in one launch
// ---------------------------------------------------------------------------
__global__ __launch_bounds__(256) void gemm_both(
        const float* __restrict__ X_n, const float* __restrict__ W_n,
        const float* __restrict__ dinv_n, float* __restrict__ hs_n, int N_n, int Gn,
        const float* __restrict__ X_d, const float* __restrict__ W_d,
        const float* __restrict__ dinv_d, float* __restrict__ hs_d, int N_d) {
    __shared__ float Wt[32][FD];
    __shared__ float At[32][36];

    const float *X, *W, *dinv; float* hs; int N, r0;
    if (blockIdx.x < Gn) { X = X_n; W = W_n; dinv = dinv_n; hs = hs_n; N = N_n;
                           r0 = blockIdx.x * 32; }
    else                 { X = X_d; W = W_d; dinv = dinv_d; hs = hs_d; N = N_d;
                           r0 = (blockIdx.x - Gn) * 32; }

    const int tid = threadIdx.x;
    const int tx = tid & 31;
    const int ty = tid >> 5;

    float acc[4][4] = {};

    for (int kt = 0; kt < FD; kt += 32) {
        __syncthreads();
        #pragma unroll
        for (int i = 0; i < 4; i++) {
            int idx = tid + i * 256;
            int k   = idx >> 5;
            int c4  = idx & 31;
            float4 w = *(const float4*)&W[(size_t)(kt + k) * FD + c4 * 4];
            *(float4*)&Wt[k][c4 * 4] = w;
        }
        {
            int row_l = tid >> 3;
            int kq    = tid & 7;
            int row   = r0 + row_l;
            float4 a = make_float4(0.f, 0.f, 0.f, 0.f);
            if (row < N) a = *(const float4*)&X[(size_t)row * FD + kt + kq * 4];
            At[kq * 4 + 0][row_l] = a.x;
            At[kq * 4 + 1][row_l] = a.y;
            At[kq * 4 + 2][row_l] = a.z;
            At[kq * 4 + 3][row_l] = a.w;
        }
        __syncthreads();
        #pragma unroll
        for (int k = 0; k < 32; k++) {
            float4 av4 = *(const float4*)&At[k][ty * 4];
            float4 wv4 = *(const float4*)&Wt[k][tx * 4];
            float av[4] = {av4.x, av4.y, av4.z, av4.w};
            float wv[4] = {wv4.x, wv4.y, wv4.z, wv4.w};
            #pragma unroll
            for (int i = 0; i < 4; i++)
                #pragma unroll
                for (int j = 0; j < 4; j++)
                    acc[i][j] = fmaf(av[i], wv[j], acc[i][j]);
        }
    }

    #pragma unroll
    for (int i = 0; i < 4; i++) {
        int row = r0 + ty * 4 + i;
        if (row < N) {
            float dv = dinv[row];
            float4 hv = make_float4(acc[i][0] * dv, acc[i][1] * dv,
                                    acc[i][2] * dv, acc[i][3] * dv);
            *(float4*)&hs[(size_t)row * FD + tx * 4] = hv;
        }
    }
}

// ---------------------------------------------------------------------------
// 5) gather + relu + l2norm + column-mean accumulate.
//    HALF-WAVE (32 lanes) per node, float4 per lane; both graphs in one
//    grid-stride loop; 4-deep pipelined edge loop.
// ---------------------------------------------------------------------------
__global__ __launch_bounds__(256) void gather_reduce_both(
        const float* __restrict__ hs_n, const float* __restrict__ dinv_n,
        const int* __restrict__ off_n, const int2* __restrict__ el_n,
        const float* __restrict__ b_n, int N_n,
        const float* __restrict__ hs_d, const float* __restrict__ dinv_d,
        const int* __restrict__ off_d, const int2* __restrict__ el_d,
        const float* __restrict__ b_d, int N_d,
        float* __restrict__ vec) {
    __shared__ float accw[8][2 * FD];   // 8 half-waves x 256 floats = 8 KB
    const int tid  = threadIdx.x;
    const int hw   = tid >> 5;          // half-wave id in block, 0..7
    const int lane = tid & 31;          // lane within half-wave

    float4 bbn = *(const float4*)&b_n[lane * 4];
    float4 bbd = *(const float4*)&b_d[lane * 4];
    float an0 = 0.f, an1 = 0.f, an2 = 0.f, an3 = 0.f;
    float ad0 = 0.f, ad1 = 0.f, ad2 = 0.f, ad3 = 0.f;

    const int total = N_n + N_d;
    const int stride = gridDim.x * 8;
    for (int t = blockIdx.x * 8 + hw; t < total; t += stride) {
        const bool isn = t < N_n;
        const int i = isn ? t : t - N_n;
        const float* hs   = isn ? hs_n : hs_d;
        const float* dinv = isn ? dinv_n : dinv_d;
        const int*   off  = isn ? off_n : off_d;
        const int2*  el   = isn ? el_n : el_d;

        float dv = dinv[i];
        float4 h = *(const float4*)&hs[(size_t)i * FD + lane * 4];
        float x0 = h.x * dv, x1 = h.y * dv, x2 = h.z * dv, x3 = h.w * dv;
        int js = i ? off[i - 1] : 0;
        int je = off[i];
        int j = js;
        for (; j + 4 <= je; j += 4) {
            int2 p0 = el[j], p1 = el[j + 1], p2 = el[j + 2], p3 = el[j + 3];
            float4 h0 = *(const float4*)&hs[(size_t)p0.x * FD + lane * 4];
            float4 h1 = *(const float4*)&hs[(size_t)p1.x * FD + lane * 4];
            float4 h2 = *(const float4*)&hs[(size_t)p2.x * FD + lane * 4];
            float4 h3 = *(const float4*)&hs[(size_t)p3.x * FD + lane * 4];
            float w0 = __int_as_float(p0.y) * dv;
            float w1 = __int_as_float(p1.y) * dv;
            float w2 = __int_as_float(p2.y) * dv;
            float w3 = __int_as_float(p3.y) * dv;
            x0 = fmaf(h0.x, w0, x0); x1 = fmaf(h0.y, w0, x1);
            x2 = fmaf(h0.z, w0, x2); x3 = fmaf(h0.w, w0, x3);
            x0 = fmaf(h1.x, w1, x0); x1 = fmaf(h1.y, w1, x1);
            x2 = fmaf(h1.z, w1, x2); x3 = fmaf(h1.w, w1, x3);
            x0 = fmaf(h2.x, w2, x0); x1 = fmaf(h2.y, w2, x1);
            x2 = fmaf(h2.z, w2, x2); x3 = fmaf(h2.w, w2, x3);
            x0 = fmaf(h3.x, w3, x0); x1 = fmaf(h3.y, w3, x1);
            x2 = fmaf(h3.z, w3, x2); x3 = fmaf(h3.w, w3, x3);
        }
        if (j + 2 <= je) {
            int2 p0 = el[j], p1 = el[j + 1];
            float4 h0 = *(const float4*)&hs[(size_t)p0.x * FD + lane * 4];
            float4 h1 = *(const float4*)&hs[(size_t)p1.x * FD + lane * 4];
            float w0 = __int_as_float(p0.y) * dv;
            float w1 = __int_as_float(p1.y) * dv;
            x0 = fmaf(h0.x, w0, x0); x1 = fmaf(h0.y, w0, x1);
            x2 = fmaf(h0.z, w0, x2); x3 = fmaf(h0.w, w0, x3);
            x0 = fmaf(h1.x, w1, x0); x1 = fmaf(h1.y, w1, x1);
            x2 = fmaf(h1.z, w1, x2); x3 = fmaf(h1.w, w1, x3);
            j += 2;
        }
        if (j < je) {
            int2 p0 = el[j];
            float4 h0 = *(const float4*)&hs[(size_t)p0.x * FD + lane * 4];
            float w0 = __int_as_float(p0.y) * dv;
            x0 = fmaf(h0.x, w0, x0); x1 = fmaf(h0.y, w0, x1);
            x2 = fmaf(h0.z, w0, x2); x3 = fmaf(h0.w, w0, x3);
        }
        float4 bb = isn ? bbn : bbd;
        x0 = fmaxf(x0 + bb.x, 0.f);
        x1 = fmaxf(x1 + bb.y, 0.f);
        x2 = fmaxf(x2 + bb.z, 0.f);
        x3 = fmaxf(x3 + bb.w, 0.f);
        float ss = fmaf(x0, x0, fmaf(x1, x1, fmaf(x2, x2, x3 * x3)));
        #pragma unroll
        for (int o = 16; o; o >>= 1) ss += __shfl_xor(ss, o);  // within half-wave
        float inv = 1.0f / fmaxf(sqrtf(ss), 1e-12f);
        if (isn) {
            an0 = fmaf(x0, inv, an0); an1 = fmaf(x1, inv, an1);
            an2 = fmaf(x2, inv, an2); an3 = fmaf(x3, inv, an3);
        } else {
            ad0 = fmaf(x0, inv, ad0); ad1 = fmaf(x1, inv, ad1);
            ad2 = fmaf(x2, inv, ad2); ad3 = fmaf(x3, inv, ad3);
        }
    }
    accw[hw][lane * 4 + 0] = an0;
    accw[hw][lane * 4 + 1] = an1;
    accw[hw][lane * 4 + 2] = an2;
    accw[hw][lane * 4 + 3] = an3;
    accw[hw][FD + lane * 4 + 0] = ad0;
    accw[hw][FD + lane * 4 + 1] = ad1;
    accw[hw][FD + lane * 4 + 2] = ad2;
    accw[hw][FD + lane * 4 + 3] = ad3;
    __syncthreads();
    {
        float s = accw[0][tid] + accw[1][tid] + accw[2][tid] + accw[3][tid]
                + accw[4][tid] + accw[5][tid] + accw[6][tid] + accw[7][tid];
        unsafeAtomicAdd(&vec[tid], s);
    }
}

// ---------------------------------------------------------------------------
// 6) final MLP: combined(256) @ W1(256x64) + b1 -> relu -> @ W2(64x1) + b2
//    256 threads: 4-way split over K, LDS reduce.
// ---------------------------------------------------------------------------
__global__ __launch_bounds__(256) void final_kernel(
        const float* __restrict__ vec,
        const float* __restrict__ W1, const float* __restrict__ b1,
        const float* __restrict__ W2, const float* __restrict__ b2,
        float* __restrict__ out, float invNnet, float invNdag) {
    __shared__ float part[4][64];
    int j = threadIdx.x & 63;
    int q = threadIdx.x >> 6;
    float h = 0.f;
    int k0 = q * 64;
    float scale0 = (k0 < 128) ? invNnet : invNdag;
    for (int k = k0; k < k0 + 64; k++) {
        float sc = (k < 128) ? invNnet : invNdag; (void)scale0;
        h = fmaf(vec[k] * sc, W1[k * 64 + j], h);
    }
    part[q][j] = h;
    __syncthreads();
    if (threadIdx.x < 64) {
        float hh = b1[j] + part[0][j] + part[1][j] + part[2][j] + part[3][j];
        hh = fmaxf(hh, 0.f);
        float p = hh * W2[j];
        #pragma unroll
        for (int o = 32; o; o >>= 1) p += __shfl_xor(p, o);
        if (j == 0) out[0] = p + b2[0];
    }
}

// ---------------------------------------------------------------------------
extern "C" void kernel_launch(void* const* d_in, const int* in_sizes, int n_in,
                              void* d_out, int out_size, void* d_ws, size_t ws_size,
                              hipStream_t stream) {
    const float* net_feat = (const float*)d_in[0];
    const int*   net_ei   = (const int*)d_in[1];
    const float* net_ew   = (const float*)d_in[2];
    const float* dag_feat = (const float*)d_in[3];
    const int*   dag_ei   = (const int*)d_in[4];
    const float* dag_ew   = (const float*)d_in[5];
    const float* W_net    = (const float*)d_in[6];
    const float* b_net    = (const float*)d_in[7];
    const float* W_dag    = (const float*)d_in[8];
    const float* b_dag    = (const float*)d_in[9];
    const float* W1       = (const float*)d_in[10];
    const float* b1       = (const float*)d_in[11];
    const float* W2       = (const float*)d_in[12];
    const float* b2       = (const float*)d_in[13];

    const int N_net = in_sizes[0] / FD;
    const int E_net = in_sizes[2];
    const int N_dag = in_sizes[3] / FD;
    const int E_dag = in_sizes[5];
    const int Bn  = (N_net + 255) / 256, Bd  = (N_dag + 255) / 256;
    const int GBn = (E_net + 255) / 256, GBd = (E_dag + 255) / 256;
    const int Gn  = (N_net + 31) / 32,  Gd  = (N_dag + 31) / 32;

    float* ws = (float*)d_ws;
    size_t o = 0;
    float* hs_net = ws + o; o += (size_t)N_net * FD;
    float* hs_dag = ws + o; o += (size_t)N_dag * FD;
    // zeroed region: deg_net | deg_dag | cnt_net | cnt_dag | vec
    float* deg_net = ws + o; o += N_net;
    float* deg_dag = ws + o; o += N_dag;
    int*   cnt_net = (int*)(ws + o); o += N_net;
    int*   cnt_dag = (int*)(ws + o); o += N_dag;
    float* vec     = ws + o; o += 256;
    size_t zcount = (size_t)2 * (N_net + N_dag) + 256;
    int*   off_net  = (int*)(ws + o); o += N_net;
    int*   off_dag  = (int*)(ws + o); o += N_dag;
    int*   bsum_net = (int*)(ws + o); o += (size_t)(Bn + 1) & ~(size_t)1;
    int*   bsum_dag = (int*)(ws + o); o += (size_t)(Bd + 1) & ~(size_t)1;
    int2*  elist_net = (int2*)(ws + o); o += (size_t)2 * E_net;
    int2*  elist_dag = (int2*)(ws + o); o += (size_t)2 * E_dag;

    hipMemsetAsync(deg_net, 0, zcount * sizeof(float), stream);

    degcnt_both<<<GBn + GBd, 256, 0, stream>>>(net_ei, net_ew, deg_net, cnt_net, E_net, GBn,
                                               dag_ei, dag_ew, deg_dag, cnt_dag, E_dag);

    scan1_both<<<Bn + Bd, 256, 0, stream>>>(cnt_net, bsum_net, deg_net, N_net, Bn,
                                            cnt_dag, bsum_dag, deg_dag, N_dag);
    scan2_both<<<2, 64, 0, stream>>>(bsum_net, Bn, bsum_dag, Bd);
    scan3_both<<<Bn + Bd, 256, 0, stream>>>(cnt_net, bsum_net, off_net, N_net, Bn,
                                            cnt_dag, bsum_dag, off_dag, N_dag);

    bucket_both<<<GBn + GBd, 256, 0, stream>>>(net_ei, net_ew, off_net, elist_net, E_net, GBn,
                                               dag_ei, dag_ew, off_dag, elist_dag, E_dag);

    gemm_both<<<Gn + Gd, 256, 0, stream>>>(net_feat, W_net, deg_net, hs_net, N_net, Gn,
                                           dag_feat, W_dag, deg_dag, hs_dag, N_dag);

    gather_reduce_both<<<2048, 256, 0, stream>>>(
        hs_net, deg_net, off_net, elist_net, b_net, N_net,
        hs_dag, deg_dag, off_dag, elist_dag, b_dag, N_dag, vec);

    final_kernel<<<1, 256, 0, stream>>>(vec, W1, b1, W2, b2, (float*)d_out,
                                        1.0f / (float)N_net, 1.0f / (float)N_dag);
}